// Round 2
// baseline (1394.172 us; speedup 1.0000x reference)
//
#include <hip/hip_runtime.h>

// DyGPrompt pretrain: 2-layer temporal graph attention.
// Structure (round 2):
//  - Edge projections eliminated algebraically (round 1), but now with
//    composite QT weights:  QT_h = qin @ (Wt_h q_w)^T + Wt_h bq  — removes
//    the Q1->QT dependency so each layer's Q-side is ONE fused GEMM dispatch
//    producing {Q, QT0, QT1} (+TV in layer 1, +H1K/H1V in layer 2).
//  - qin gather+add (nf[nodes]+t, h1[jmap]+t) folded into the GEMM A-loader.
//  - All small GEMMs nt-split x3 (grid.y) for occupancy (752->2256 waves).
//  - Attention: one wave per sample (4/block, 12000 waves). Scores via
//    32-lane-per-head coalesced dot + shuffle reduce; softmax in-wave;
//    output/agg via 64-lane coalesced passes. No ef LDS staging.

#define NSMP   12000
#define KNB    20
#define EDIM   172
#define HDIM   86
#define NNODES 100000
#define NT_N   11     // ceil(172/16) n-tiles
#define KS_N   6      // ceil(172/32) k-steps
#define NTBL   8
#define TBL_SZ (NT_N * KS_N * 64 * 8)   // elements per pre-swizzled table
#define MM     (EDIM * EDIM)            // 29584

typedef unsigned int uint;
typedef unsigned short ushort;
typedef __attribute__((ext_vector_type(8))) short  bf16x8;
typedef __attribute__((ext_vector_type(4))) float  f32x4;

static __device__ __forceinline__ ushort f2bf(float f) {
    uint u = __float_as_uint(f);
    uint r = (u + 0x7fffu + ((u >> 16) & 1u)) >> 16;   // RNE, finite inputs
    return (ushort)r;
}
static __device__ __forceinline__ float bf2f(ushort b) {
    return __uint_as_float(((uint)b) << 16);
}

// A-fragments for a 16-row block: row = lane&15, k = s*32 + quad*8 + j.
static __device__ __forceinline__ void load_afrag(
    const float* __restrict__ rowp, int quad, bf16x8* af)
{
    const float* ap = rowp + quad * 8;
    #pragma unroll
    for (int s = 0; s < KS_N - 1; s++) {
        float4 f0 = *(const float4*)(ap + s * 32);
        float4 f1 = *(const float4*)(ap + s * 32 + 4);
        af[s][0] = f2bf(f0.x); af[s][1] = f2bf(f0.y);
        af[s][2] = f2bf(f0.z); af[s][3] = f2bf(f0.w);
        af[s][4] = f2bf(f1.x); af[s][5] = f2bf(f1.y);
        af[s][6] = f2bf(f1.z); af[s][7] = f2bf(f1.w);
    }
    const int kt = EDIM - 160 - quad * 8;   // 12, 4, -4, -12
    #pragma unroll
    for (int j = 0; j < 8; j++)
        af[KS_N - 1][j] = (j < kt) ? (short)f2bf(ap[160 + j]) : (short)0;
}

// Same, but A = rowp + addp (elementwise), bf16-rounded after the sum.
static __device__ __forceinline__ void load_afrag2(
    const float* __restrict__ rowp, const float* __restrict__ addp,
    int quad, bf16x8* af)
{
    const float* ap = rowp + quad * 8;
    const float* bp = addp + quad * 8;
    #pragma unroll
    for (int s = 0; s < KS_N - 1; s++) {
        float4 f0 = *(const float4*)(ap + s * 32);
        float4 f1 = *(const float4*)(ap + s * 32 + 4);
        float4 g0 = *(const float4*)(bp + s * 32);
        float4 g1 = *(const float4*)(bp + s * 32 + 4);
        af[s][0] = f2bf(f0.x + g0.x); af[s][1] = f2bf(f0.y + g0.y);
        af[s][2] = f2bf(f0.z + g0.z); af[s][3] = f2bf(f0.w + g0.w);
        af[s][4] = f2bf(f1.x + g1.x); af[s][5] = f2bf(f1.y + g1.y);
        af[s][6] = f2bf(f1.z + g1.z); af[s][7] = f2bf(f1.w + g1.w);
    }
    const int kt = EDIM - 160 - quad * 8;
    #pragma unroll
    for (int j = 0; j < 8; j++)
        af[KS_N - 1][j] = (j < kt) ? (short)f2bf(ap[160 + j] + bp[160 + j]) : (short)0;
}

// ---------------- time encoding ----------------
__global__ __launch_bounds__(256) void time_enc_kernel(
    const float* __restrict__ ts, const float* __restrict__ tw,
    const float* __restrict__ tb, float* __restrict__ t)
{
    int i = blockIdx.x * 256 + threadIdx.x;
    if (i < NSMP * EDIM) {
        int b = i / EDIM, e = i - b * EDIM;
        t[i] = cosf(ts[b] * tw[e] + tb[e]);
    }
}

// ---------------- winner scatter (last write wins) ----------------
__global__ __launch_bounds__(256) void winner_init_kernel(int* __restrict__ w)
{
    int i = blockIdx.x * 256 + threadIdx.x;
    if (i < NNODES) w[i] = -1;
}
__global__ __launch_bounds__(256) void winner_scatter_kernel(
    const int* __restrict__ nodes, int* __restrict__ w)
{
    int i = blockIdx.x * 256 + threadIdx.x;
    if (i < NSMP) atomicMax(&w[nodes[i]], i);
}
__global__ __launch_bounds__(256) void jmap_kernel(
    const int* __restrict__ nodes, const int* __restrict__ w,
    int* __restrict__ jmap)
{
    int i = blockIdx.x * 256 + threadIdx.x;
    if (i < NSMP) jmap[i] = w[nodes[i]];
}

// ---------------- composite matrices ----------------
// Cbuf: [0]=M0 [1]=M1 [2]=Wqt0 [3]=Wqt1 (172x172 each), then bqt0,bqt1 (172).
//   M_h[i][j]   = sum_d out_w[i][h*86+d] * v_w[h*86+d][172+j]
//   Wqt_h[i][j] = sum_d k_w[h*86+d][172+i] * q_w[h*86+d][j]
//   bqt_h[i]    = sum_d k_w[h*86+d][172+i] * bq[h*86+d]
__global__ __launch_bounds__(256) void composites_kernel(
    const float* __restrict__ out_w, const float* __restrict__ v_w,
    const float* __restrict__ k_w, const float* __restrict__ q_w,
    const float* __restrict__ bq, float* __restrict__ Cbuf)
{
    int idx = blockIdx.x * 256 + threadIdx.x;
    if (idx < 2 * MM) {
        int h = idx / MM, r = idx - h * MM, i = r / EDIM, j = r - i * EDIM;
        float s = 0.f;
        for (int d = 0; d < HDIM; d++)
            s += out_w[i * EDIM + h * HDIM + d] *
                 v_w[(long)(h * HDIM + d) * (2 * EDIM) + EDIM + j];
        Cbuf[idx] = s;
    } else if (idx < 4 * MM) {
        int tt = idx - 2 * MM;
        int h = tt / MM, r = tt - h * MM, i = r / EDIM, j = r - i * EDIM;
        float s = 0.f;
        for (int d = 0; d < HDIM; d++)
            s += k_w[(long)(h * HDIM + d) * (2 * EDIM) + EDIM + i] *
                 q_w[(h * HDIM + d) * EDIM + j];
        Cbuf[idx] = s;
    } else if (idx < 4 * MM + 2 * EDIM) {
        int tt = idx - 4 * MM;
        int h = tt / EDIM, i = tt - h * EDIM;
        float s = 0.f;
        for (int d = 0; d < HDIM; d++)
            s += k_w[(long)(h * HDIM + d) * (2 * EDIM) + EDIM + i] * bq[h * HDIM + d];
        Cbuf[idx] = s;
    }
}

// ---------------- weight pre-swizzle: f32 -> bf16 B-fragments ----
// frag (nt,s,lane) at ((nt*KS_N+s)*64+lane)*8; elem j:
//   W[nt*16 + (lane&15)][s*32 + (lane>>4)*8 + j]  (0 if OOB)
// Tables: 0=q_w 1=out_w 2=k_wE 3=v_wE 4=Wqt0 5=Wqt1 6=M0 7=M1
__global__ __launch_bounds__(256) void preswizzle_kernel(
    const float* __restrict__ q_w, const float* __restrict__ out_w,
    const float* __restrict__ k_w, const float* __restrict__ v_w,
    const float* __restrict__ Cbuf, ushort* __restrict__ BF)
{
    int gid = blockIdx.x * 256 + threadIdx.x;
    int total = NTBL * NT_N * KS_N * 64;
    if (gid >= total) return;
    int tbl  = gid / (NT_N * KS_N * 64);
    int rem  = gid - tbl * (NT_N * KS_N * 64);
    int lane = rem & 63;
    int fs   = rem >> 6;          // nt*KS_N + s
    int s    = fs % KS_N;
    int nt   = fs / KS_N;
    int n    = nt * 16 + (lane & 15);
    int k0   = s * 32 + (lane >> 4) * 8;
    ushort* dst = BF + (size_t)tbl * TBL_SZ + (size_t)(fs * 64 + lane) * 8;
    #pragma unroll
    for (int j = 0; j < 8; j++) {
        int k = k0 + j;
        float val = 0.f;
        if (n < EDIM && k < EDIM) {
            switch (tbl) {
                case 0: val = q_w[(long)n * EDIM + k]; break;
                case 1: val = out_w[(long)n * EDIM + k]; break;
                case 2: val = k_w[(long)n * 2 * EDIM + k]; break;
                case 3: val = v_w[(long)n * 2 * EDIM + k]; break;
                case 4: val = Cbuf[2 * MM + (long)n * EDIM + k]; break;
                case 5: val = Cbuf[3 * MM + (long)n * EDIM + k]; break;
                case 6: val = Cbuf[0 * MM + (long)n * EDIM + k]; break;
                default: val = Cbuf[1 * MM + (long)n * EDIM + k]; break;
            }
        }
        dst[j] = f2bf(val);
    }
}

// ---------------- NodeK/V GEMM (RB=4, bf16 out) ----------------
__global__ __launch_bounds__(256) void gemm_nodekv_kernel(
    const float* __restrict__ A, int M,
    const ushort* __restrict__ BF1, const ushort* __restrict__ BF2,
    ushort* __restrict__ C1h, ushort* __restrict__ C2h)
{
    const int lane = threadIdx.x & 63;
    const int wave = threadIdx.x >> 6;
    const int col  = lane & 15;
    const int quad = lane >> 4;
    const int m0   = (blockIdx.x * 4 + wave) * 64;
    if (m0 >= M) return;

    bf16x8 af[4][KS_N];
    bool rv[4];
    #pragma unroll
    for (int rb = 0; rb < 4; rb++) {
        int mr = m0 + rb * 16;
        rv[rb] = (mr < M);
        long arow = rv[rb] ? (long)(mr + col) : 0;
        load_afrag(A + arow * EDIM, quad, af[rb]);
    }

    #pragma unroll
    for (int nt = 0; nt < NT_N; nt++) {
        const ushort* bp1 = BF1 + (size_t)(nt * KS_N * 64 + lane) * 8;
        const ushort* bp2 = BF2 + (size_t)(nt * KS_N * 64 + lane) * 8;
        f32x4 acc1[4], acc2[4];
        #pragma unroll
        for (int rb = 0; rb < 4; rb++) {
            acc1[rb] = {0.f, 0.f, 0.f, 0.f};
            acc2[rb] = {0.f, 0.f, 0.f, 0.f};
        }
        #pragma unroll
        for (int s = 0; s < KS_N; s++) {
            bf16x8 b1 = *(const bf16x8*)(bp1 + (size_t)s * 64 * 8);
            bf16x8 b2 = *(const bf16x8*)(bp2 + (size_t)s * 64 * 8);
            #pragma unroll
            for (int rb = 0; rb < 4; rb++) {
                acc1[rb] = __builtin_amdgcn_mfma_f32_16x16x32_bf16(af[rb][s], b1, acc1[rb], 0, 0, 0);
                acc2[rb] = __builtin_amdgcn_mfma_f32_16x16x32_bf16(af[rb][s], b2, acc2[rb], 0, 0, 0);
            }
        }
        const int n = nt * 16 + col;
        if (n < EDIM) {
            #pragma unroll
            for (int rb = 0; rb < 4; rb++) {
                if (!rv[rb]) continue;
                #pragma unroll
                for (int r = 0; r < 4; r++) {
                    long ci = (long)(m0 + rb * 16 + quad * 4 + r) * EDIM + n;
                    C1h[ci] = f2bf(acc1[rb][r]);
                    C2h[ci] = f2bf(acc2[rb][r]);
                }
            }
        }
    }
}

// ---------------- fused multi-output GEMM ----------------
// A1 (gathered via A1idx, + A1add elementwise) -> O1a/O1b/O1c via B1a/b/c.
// A2 (direct) -> O2a/O2b via B2a/b. nt range from blockIdx.y (x3 split).
__global__ __launch_bounds__(256) void fused_gemm_kernel(
    const float* __restrict__ A1, const int* __restrict__ A1idx,
    const float* __restrict__ A1add, const float* __restrict__ A2, int M,
    const ushort* __restrict__ B1a, const ushort* __restrict__ B1b,
    const ushort* __restrict__ B1c,
    const float* __restrict__ bs1a, const float* __restrict__ bs1b,
    const float* __restrict__ bs1c,
    const ushort* __restrict__ B2a, const ushort* __restrict__ B2b,
    const float* __restrict__ bs2a,
    float* __restrict__ O1a, float* __restrict__ O1b, float* __restrict__ O1c,
    float* __restrict__ O2a, float* __restrict__ O2b)
{
    const int lane = threadIdx.x & 63;
    const int wave = threadIdx.x >> 6;
    const int col  = lane & 15;
    const int quad = lane >> 4;
    const int m0   = (blockIdx.x * 4 + wave) * 16;
    if (m0 >= M) return;
    int nt0 = blockIdx.y * 4;
    int nt1 = nt0 + 4; if (nt1 > NT_N) nt1 = NT_N;

    long r1 = m0 + col;
    if (A1idx) r1 = (long)A1idx[r1];
    bf16x8 af1[KS_N];
    if (A1add) load_afrag2(A1 + r1 * EDIM, A1add + (long)(m0 + col) * EDIM, quad, af1);
    else       load_afrag(A1 + r1 * EDIM, quad, af1);
    bf16x8 af2[KS_N];
    if (A2) load_afrag(A2 + (long)(m0 + col) * EDIM, quad, af2);

    for (int nt = nt0; nt < nt1; nt++) {
        const size_t boff = (size_t)(nt * KS_N * 64 + lane) * 8;
        f32x4 acc1 = {0.f,0.f,0.f,0.f}, acc2 = acc1, acc3 = acc1, acc4 = acc1, acc5 = acc1;
        #pragma unroll
        for (int s = 0; s < KS_N; s++) {
            const size_t so = boff + (size_t)s * 64 * 8;
            acc1 = __builtin_amdgcn_mfma_f32_16x16x32_bf16(af1[s], *(const bf16x8*)(B1a + so), acc1, 0, 0, 0);
            if (B1b) acc2 = __builtin_amdgcn_mfma_f32_16x16x32_bf16(af1[s], *(const bf16x8*)(B1b + so), acc2, 0, 0, 0);
            if (B1c) acc3 = __builtin_amdgcn_mfma_f32_16x16x32_bf16(af1[s], *(const bf16x8*)(B1c + so), acc3, 0, 0, 0);
            if (B2a) acc4 = __builtin_amdgcn_mfma_f32_16x16x32_bf16(af2[s], *(const bf16x8*)(B2a + so), acc4, 0, 0, 0);
            if (B2b) acc5 = __builtin_amdgcn_mfma_f32_16x16x32_bf16(af2[s], *(const bf16x8*)(B2b + so), acc5, 0, 0, 0);
        }
        const int n = nt * 16 + col;
        if (n < EDIM) {
            const float b1 = bs1a ? bs1a[n] : 0.f;
            const float b2 = bs1b ? bs1b[n] : 0.f;
            const float b3 = bs1c ? bs1c[n] : 0.f;
            const float b4 = bs2a ? bs2a[n] : 0.f;
            #pragma unroll
            for (int r = 0; r < 4; r++) {
                long ci = (long)(m0 + quad * 4 + r) * EDIM + n;
                O1a[ci] = acc1[r] + b1;
                if (O1b) O1b[ci] = acc2[r] + b2;
                if (O1c) O1c[ci] = acc3[r] + b3;
                if (O2a) O2a[ci] = acc4[r] + b4;
                if (O2b) O2b[ci] = acc5[r];
            }
        }
    }
}

// ---------------- output projection: C = A1@out_w^T + agg0@M0^T + agg1@M1^T + bias
__global__ __launch_bounds__(256) void gemm_out3_kernel(
    const float* __restrict__ A1,   // AO, lda = EDIM
    const float* __restrict__ A2,   // AGG, lda = 2*EDIM (two 172-halves)
    int M,
    const ushort* __restrict__ BFo, const ushort* __restrict__ BFm0,
    const ushort* __restrict__ BFm1,
    const float* __restrict__ bias, float* __restrict__ C)
{
    const int lane = threadIdx.x & 63;
    const int wave = threadIdx.x >> 6;
    const int col  = lane & 15;
    const int quad = lane >> 4;
    const int m0   = (blockIdx.x * 4 + wave) * 16;
    if (m0 >= M) return;
    int nt0 = blockIdx.y * 4;
    int nt1 = nt0 + 4; if (nt1 > NT_N) nt1 = NT_N;
    const long arow = m0 + col;

    bf16x8 afo[KS_N], afa[KS_N], afb[KS_N];
    load_afrag(A1 + arow * EDIM, quad, afo);
    load_afrag(A2 + arow * 2 * EDIM, quad, afa);
    load_afrag(A2 + arow * 2 * EDIM + EDIM, quad, afb);

    for (int nt = nt0; nt < nt1; nt++) {
        const size_t boff = (size_t)(nt * KS_N * 64 + lane) * 8;
        f32x4 acc = {0.f, 0.f, 0.f, 0.f};
        #pragma unroll
        for (int s = 0; s < KS_N; s++) {
            const size_t so = boff + (size_t)s * 64 * 8;
            acc = __builtin_amdgcn_mfma_f32_16x16x32_bf16(afo[s], *(const bf16x8*)(BFo  + so), acc, 0, 0, 0);
            acc = __builtin_amdgcn_mfma_f32_16x16x32_bf16(afa[s], *(const bf16x8*)(BFm0 + so), acc, 0, 0, 0);
            acc = __builtin_amdgcn_mfma_f32_16x16x32_bf16(afb[s], *(const bf16x8*)(BFm1 + so), acc, 0, 0, 0);
        }
        const int n = nt * 16 + col;
        if (n < EDIM) {
            const float bb = bias ? bias[n] : 0.f;
            #pragma unroll
            for (int r = 0; r < 4; r++) {
                long ci = (long)(m0 + quad * 4 + r) * EDIM + n;
                C[ci] = acc[r] + bb;
            }
        }
    }
}

// ---------------- per-sample attention: one wave per sample ----------------
__global__ __launch_bounds__(256) void attn_kernel(
    const int* __restrict__ neighbors, const int* __restrict__ eidx,
    const float* __restrict__ Q, const float* __restrict__ QT0,
    const float* __restrict__ QT1, const float* __restrict__ TV,
    const float* __restrict__ edgef,
    const int* __restrict__ winner,
    const ushort* __restrict__ NodeK, const ushort* __restrict__ NodeV,
    const float* __restrict__ H1K, const float* __restrict__ H1V,
    float* __restrict__ AO, float* __restrict__ AGG)
{
    const int wv   = threadIdx.x >> 6;
    const int lane = threadIdx.x & 63;
    const int b    = blockIdx.x * 4 + wv;       // NSMP % 4 == 0

    __shared__ float sq[4][3][176];             // [wave][q, qt0, qt1]
    __shared__ float swv[4][2][24];             // scores -> weights
    __shared__ int   smeta[4][4][20];           // snb, sei, swin, spad

    int* snb  = smeta[wv][0];
    int* sei  = smeta[wv][1];
    int* swin = smeta[wv][2];
    int* spad = smeta[wv][3];

    int nb = 1;
    if (lane < KNB) nb = neighbors[b * KNB + lane];
    unsigned long long pm = __ballot(nb == 0);
    bool allpad = (__popcll(pm & ((1ull << KNB) - 1)) == KNB);
    if (lane < KNB) {
        snb[lane]  = nb;
        sei[lane]  = eidx[b * KNB + lane];
        swin[lane] = winner ? winner[nb] : -1;
        spad[lane] = (nb == 0 && !(allpad && lane == 0)) ? 1 : 0;
    }
    #pragma unroll
    for (int p = 0; p < 3; p++) {
        int i = p * 64 + lane;
        if (i < EDIM) {
            sq[wv][0][i] = Q  [(long)b * EDIM + i];
            sq[wv][1][i] = QT0[(long)b * EDIM + i];
            sq[wv][2][i] = QT1[(long)b * EDIM + i];
        }
    }
    __syncthreads();

    // ---- scores: 32-lane group per head ----
    const int h  = lane >> 5;
    const int sl = lane & 31;
    const float* qn = sq[wv][0] + h * HDIM;
    const float* qt = sq[wv][1 + h];
    for (int kk = 0; kk < KNB; kk++) {
        int ww  = swin[kk];
        int nbk = snb[kk];
        float s = 0.f;
        if (ww >= 0) {
            const float* kp = H1K + (long)ww * EDIM + h * HDIM;
            s += kp[sl] * qn[sl] + kp[sl + 32] * qn[sl + 32];
            if (sl < HDIM - 64) s += kp[sl + 64] * qn[sl + 64];
        } else {
            const ushort* kp = NodeK + (long)nbk * EDIM + h * HDIM;
            s += bf2f(kp[sl]) * qn[sl] + bf2f(kp[sl + 32]) * qn[sl + 32];
            if (sl < HDIM - 64) s += bf2f(kp[sl + 64]) * qn[sl + 64];
        }
        const float* ep = edgef + (long)sei[kk] * EDIM;
        #pragma unroll
        for (int c = 0; c < 5; c++) s += ep[sl + c * 32] * qt[sl + c * 32];
        if (sl < 12) s += ep[sl + 160] * qt[sl + 160];
        s += __shfl_xor(s, 1, 64);
        s += __shfl_xor(s, 2, 64);
        s += __shfl_xor(s, 4, 64);
        s += __shfl_xor(s, 8, 64);
        s += __shfl_xor(s, 16, 64);
        if (sl == 0)
            swv[wv][h][kk] = spad[kk] ? -1e9f : (s * 0.10783277320343841f);  // 1/sqrt(86)
    }
    __syncthreads();

    // ---- softmax per head, in-wave ----
    {
        float v  = (sl < KNB) ? swv[wv][h][sl] : -1e30f;
        float mx = v;
        mx = fmaxf(mx, __shfl_xor(mx, 1, 64));
        mx = fmaxf(mx, __shfl_xor(mx, 2, 64));
        mx = fmaxf(mx, __shfl_xor(mx, 4, 64));
        mx = fmaxf(mx, __shfl_xor(mx, 8, 64));
        mx = fmaxf(mx, __shfl_xor(mx, 16, 64));
        float ex  = (sl < KNB) ? __expf(v - mx) : 0.f;
        float sum = ex;
        sum += __shfl_xor(sum, 1, 64);
        sum += __shfl_xor(sum, 2, 64);
        sum += __shfl_xor(sum, 4, 64);
        sum += __shfl_xor(sum, 8, 64);
        sum += __shfl_xor(sum, 16, 64);
        if (sl < KNB) swv[wv][h][sl] = ex * (1.f / sum);
    }
    __syncthreads();

    // ---- output + edge aggregation: 64-lane coalesced passes ----
    #pragma unroll
    for (int p = 0; p < 3; p++) {
        int t = p * 64 + lane;
        bool act = (t < EDIM);
        int tc = act ? t : 0;
        float acc = 0.f, a0 = 0.f, a1 = 0.f;
        for (int kk = 0; kk < KNB; kk++) {
            float w0 = swv[wv][0][kk], w1 = swv[wv][1][kk];
            int ww = swin[kk];
            float vv;
            if (ww >= 0) vv = H1V[(long)ww * EDIM + tc];
            else         vv = bf2f(NodeV[(long)snb[kk] * EDIM + tc]);
            float ev = edgef[(long)sei[kk] * EDIM + tc];
            acc += (t < HDIM ? w0 : w1) * vv;
            a0 += w0 * ev;
            a1 += w1 * ev;
        }
        if (act) {
            AO [(long)b * EDIM + t]            = acc + TV[(long)b * EDIM + t];
            AGG[(long)b * 2 * EDIM + t]        = a0;
            AGG[(long)b * 2 * EDIM + EDIM + t] = a1;
        }
    }
}

extern "C" void kernel_launch(void* const* d_in, const int* in_sizes, int n_in,
                              void* d_out, int out_size, void* d_ws, size_t ws_size,
                              hipStream_t stream)
{
    const int*   nodes   = (const int*)d_in[0];
    const float* ts      = (const float*)d_in[1];
    const int*   neigh   = (const int*)d_in[2];
    const int*   edgeidx = (const int*)d_in[3];
    const float* nodef   = (const float*)d_in[4];
    const float* edgef   = (const float*)d_in[5];
    const float* time_w  = (const float*)d_in[6];
    const float* time_b  = (const float*)d_in[7];
    const float* q_w     = (const float*)d_in[8];
    const float* k_w     = (const float*)d_in[9];
    const float* v_w     = (const float*)d_in[10];
    const float* bq      = (const float*)d_in[11];
    const float* bv      = (const float*)d_in[13];
    const float* out_w   = (const float*)d_in[14];
    const float* out_b   = (const float*)d_in[15];
    float* out = (float*)d_out;

    char* wsp = (char*)d_ws;
    size_t off = 0;
    auto alloc = [&](size_t bytes) -> void* {
        void* p = wsp + off;
        off += (bytes + 255) & ~(size_t)255;
        return p;
    };
    const size_t SE = (size_t)NSMP * EDIM;
    float* t_enc = (float*)alloc(SE * 4);
    float* Qb    = (float*)alloc(SE * 4);
    float* QT0   = (float*)alloc(SE * 4);
    float* QT1   = (float*)alloc(SE * 4);
    float* TV    = (float*)alloc(SE * 4);
    float* AO    = (float*)alloc(SE * 4);
    float* H1    = (float*)alloc(SE * 4);
    float* H1K   = (float*)alloc(SE * 4);
    float* H1V   = (float*)alloc(SE * 4);
    float* AGG   = (float*)alloc((size_t)NSMP * 2 * EDIM * 4);
    float* Cbuf  = (float*)alloc((size_t)(4 * MM + 2 * EDIM) * 4);
    int*   winner = (int*)alloc((size_t)NNODES * 4);
    int*   jmap   = (int*)alloc((size_t)NSMP * 4);
    ushort* NodeK = (ushort*)alloc((size_t)NNODES * EDIM * 2);
    ushort* NodeV = (ushort*)alloc((size_t)NNODES * EDIM * 2);
    ushort* BF    = (ushort*)alloc((size_t)NTBL * TBL_SZ * 2);
    if (off > ws_size) return;

    const ushort* BFq   = BF + 0 * TBL_SZ;
    const ushort* BFout = BF + 1 * TBL_SZ;
    const ushort* BFkE  = BF + 2 * TBL_SZ;
    const ushort* BFvE  = BF + 3 * TBL_SZ;
    const ushort* BFW0  = BF + 4 * TBL_SZ;
    const ushort* BFW1  = BF + 5 * TBL_SZ;
    const ushort* BFM0  = BF + 6 * TBL_SZ;
    const ushort* BFM1  = BF + 7 * TBL_SZ;
    const float* bqt0 = Cbuf + 4 * MM;
    const float* bqt1 = Cbuf + 4 * MM + EDIM;

    dim3 blk(256);
    const int gS = (NSMP + 63) / 64;            // 188
    dim3 gSplit(gS, 3);                          // nt ranges {0-3,4-7,8-10}

    winner_init_kernel<<<(NNODES + 255) / 256, blk, 0, stream>>>(winner);
    winner_scatter_kernel<<<(NSMP + 255) / 256, blk, 0, stream>>>(nodes, winner);
    jmap_kernel<<<(NSMP + 255) / 256, blk, 0, stream>>>(nodes, winner, jmap);
    composites_kernel<<<(4 * MM + 2 * EDIM + 255) / 256, blk, 0, stream>>>(
        out_w, v_w, k_w, q_w, bq, Cbuf);
    preswizzle_kernel<<<(NTBL * NT_N * KS_N * 64 + 255) / 256, blk, 0, stream>>>(
        q_w, out_w, k_w, v_w, Cbuf, BF);
    time_enc_kernel<<<(NSMP * EDIM + 255) / 256, blk, 0, stream>>>(ts, time_w, time_b, t_enc);

    // NodeK/V (bf16 out)
    gemm_nodekv_kernel<<<(NNODES + 255) / 256, blk, 0, stream>>>(
        nodef, NNODES, BFkE, BFvE, NodeK, NodeV);

    // Layer 1 fused: A1 = nf[nodes] + t  -> Q, QT0, QT1 ; A2 = t -> TV
    fused_gemm_kernel<<<gSplit, blk, 0, stream>>>(
        nodef, nodes, t_enc, t_enc, NSMP,
        BFq, BFW0, BFW1, bq, bqt0, bqt1,
        BFvE, nullptr, bv,
        Qb, QT0, QT1, TV, nullptr);

    attn_kernel<<<NSMP / 4, blk, 0, stream>>>(neigh, edgeidx, Qb, QT0, QT1, TV,
        edgef, nullptr, NodeK, NodeV, nullptr, nullptr, AO, AGG);
    gemm_out3_kernel<<<gSplit, blk, 0, stream>>>(AO, AGG, NSMP,
        BFout, BFM0, BFM1, out_b, H1);

    // Layer 2 fused: A1 = h1[jmap] + t -> Q, QT0, QT1 ; A2 = H1 -> H1K, H1V
    fused_gemm_kernel<<<gSplit, blk, 0, stream>>>(
        H1, jmap, t_enc, H1, NSMP,
        BFq, BFW0, BFW1, bq, bqt0, bqt1,
        BFkE, BFvE, nullptr,
        Qb, QT0, QT1, H1K, H1V);

    attn_kernel<<<NSMP / 4, blk, 0, stream>>>(neigh, edgeidx, Qb, QT0, QT1, TV,
        edgef, winner, NodeK, NodeV, H1K, H1V, AO, AGG);
    gemm_out3_kernel<<<gSplit, blk, 0, stream>>>(AO, AGG, NSMP,
        BFout, BFM0, BFM1, out_b, out);
}

// Round 3
// 1007.799 us; speedup vs baseline: 1.3834x; 1.3834x over previous
//
#include <hip/hip_runtime.h>

// DyGPrompt pretrain: 2-layer temporal graph attention.
// Round 3: latency-focused.
//  - attn: 2 samples/block, 256 thr. Only ef staged in LDS (stride 173,
//    read once from HBM). Scores: 160 independent (s,kk,h,part) threads,
//    K rows padded to stride 176 (head-aligned 88) -> 11 vector loads.
//    Softmax: wave per (s,h). Output: coalesced rows, unrolled kk.
//  - GEMMs: 16 rows/wave, nt-range split across the block's 4 waves
//    (750 blocks). NodeKV: 32 rows/wave (782 blocks). jmap folded into
//    layer-2 A-gather (winner[nodes[i]]).

#define NSMP   12000
#define KNB    20
#define EDIM   172
#define HDIM   86
#define NNODES 100000
#define NT_N   11     // ceil(172/16) n-tiles
#define KS_N   6      // ceil(172/32) k-steps
#define NTBL   8
#define TBL_SZ (NT_N * KS_N * 64 * 8)
#define MM     (EDIM * EDIM)            // 29584
#define KPAD   176    // padded K/V row stride: 2 heads x 88 (pads zeroed)
#define SKP    173    // LDS ef row stride (odd -> conflict-free-ish)

typedef unsigned int uint;
typedef unsigned short ushort;
typedef __attribute__((ext_vector_type(8))) short  bf16x8;
typedef __attribute__((ext_vector_type(4))) float  f32x4;

static __device__ __forceinline__ ushort f2bf(float f) {
    uint u = __float_as_uint(f);
    uint r = (u + 0x7fffu + ((u >> 16) & 1u)) >> 16;   // RNE, finite inputs
    return (ushort)r;
}
static __device__ __forceinline__ float bf2f(ushort b) {
    return __uint_as_float(((uint)b) << 16);
}

// A-fragments for a 16-row block: row = lane&15, k = s*32 + quad*8 + j.
static __device__ __forceinline__ void load_afrag(
    const float* __restrict__ rowp, int quad, bf16x8* af)
{
    const float* ap = rowp + quad * 8;
    #pragma unroll
    for (int s = 0; s < KS_N - 1; s++) {
        float4 f0 = *(const float4*)(ap + s * 32);
        float4 f1 = *(const float4*)(ap + s * 32 + 4);
        af[s][0] = f2bf(f0.x); af[s][1] = f2bf(f0.y);
        af[s][2] = f2bf(f0.z); af[s][3] = f2bf(f0.w);
        af[s][4] = f2bf(f1.x); af[s][5] = f2bf(f1.y);
        af[s][6] = f2bf(f1.z); af[s][7] = f2bf(f1.w);
    }
    const int kt = EDIM - 160 - quad * 8;   // 12, 4, -4, -12
    #pragma unroll
    for (int j = 0; j < 8; j++)
        af[KS_N - 1][j] = (j < kt) ? (short)f2bf(ap[160 + j]) : (short)0;
}

// Same, but A = rowp + addp (elementwise), bf16-rounded after the sum.
static __device__ __forceinline__ void load_afrag2(
    const float* __restrict__ rowp, const float* __restrict__ addp,
    int quad, bf16x8* af)
{
    const float* ap = rowp + quad * 8;
    const float* bp = addp + quad * 8;
    #pragma unroll
    for (int s = 0; s < KS_N - 1; s++) {
        float4 f0 = *(const float4*)(ap + s * 32);
        float4 f1 = *(const float4*)(ap + s * 32 + 4);
        float4 g0 = *(const float4*)(bp + s * 32);
        float4 g1 = *(const float4*)(bp + s * 32 + 4);
        af[s][0] = f2bf(f0.x + g0.x); af[s][1] = f2bf(f0.y + g0.y);
        af[s][2] = f2bf(f0.z + g0.z); af[s][3] = f2bf(f0.w + g0.w);
        af[s][4] = f2bf(f1.x + g1.x); af[s][5] = f2bf(f1.y + g1.y);
        af[s][6] = f2bf(f1.z + g1.z); af[s][7] = f2bf(f1.w + g1.w);
    }
    const int kt = EDIM - 160 - quad * 8;
    #pragma unroll
    for (int j = 0; j < 8; j++)
        af[KS_N - 1][j] = (j < kt) ? (short)f2bf(ap[160 + j] + bp[160 + j]) : (short)0;
}

// ---------------- time encoding ----------------
__global__ __launch_bounds__(256) void time_enc_kernel(
    const float* __restrict__ ts, const float* __restrict__ tw,
    const float* __restrict__ tb, float* __restrict__ t)
{
    int i = blockIdx.x * 256 + threadIdx.x;
    if (i < NSMP * EDIM) {
        int b = i / EDIM, e = i - b * EDIM;
        t[i] = cosf(ts[b] * tw[e] + tb[e]);
    }
}

// ---------------- winner scatter (last write wins) ----------------
__global__ __launch_bounds__(256) void winner_init_kernel(int* __restrict__ w)
{
    int i = blockIdx.x * 256 + threadIdx.x;
    if (i < NNODES) w[i] = -1;
}
__global__ __launch_bounds__(256) void winner_scatter_kernel(
    const int* __restrict__ nodes, int* __restrict__ w)
{
    int i = blockIdx.x * 256 + threadIdx.x;
    if (i < NSMP) atomicMax(&w[nodes[i]], i);
}

// ---------------- composite matrices ----------------
// Cbuf: [0]=M0 [1]=M1 [2]=Wqt0 [3]=Wqt1 (172x172 each), then bqt0,bqt1 (172).
__global__ __launch_bounds__(256) void composites_kernel(
    const float* __restrict__ out_w, const float* __restrict__ v_w,
    const float* __restrict__ k_w, const float* __restrict__ q_w,
    const float* __restrict__ bq, float* __restrict__ Cbuf)
{
    int idx = blockIdx.x * 256 + threadIdx.x;
    if (idx < 2 * MM) {
        int h = idx / MM, r = idx - h * MM, i = r / EDIM, j = r - i * EDIM;
        float s = 0.f;
        for (int d = 0; d < HDIM; d++)
            s += out_w[i * EDIM + h * HDIM + d] *
                 v_w[(long)(h * HDIM + d) * (2 * EDIM) + EDIM + j];
        Cbuf[idx] = s;
    } else if (idx < 4 * MM) {
        int tt = idx - 2 * MM;
        int h = tt / MM, r = tt - h * MM, i = r / EDIM, j = r - i * EDIM;
        float s = 0.f;
        for (int d = 0; d < HDIM; d++)
            s += k_w[(long)(h * HDIM + d) * (2 * EDIM) + EDIM + i] *
                 q_w[(h * HDIM + d) * EDIM + j];
        Cbuf[idx] = s;
    } else if (idx < 4 * MM + 2 * EDIM) {
        int tt = idx - 4 * MM;
        int h = tt / EDIM, i = tt - h * EDIM;
        float s = 0.f;
        for (int d = 0; d < HDIM; d++)
            s += k_w[(long)(h * HDIM + d) * (2 * EDIM) + EDIM + i] * bq[h * HDIM + d];
        Cbuf[idx] = s;
    }
}

// ---------------- weight pre-swizzle: f32 -> bf16 B-fragments ----
// Tables: 0=q_w 1=out_w 2=k_wE 3=v_wE 4=Wqt0 5=Wqt1 6=M0 7=M1
__global__ __launch_bounds__(256) void preswizzle_kernel(
    const float* __restrict__ q_w, const float* __restrict__ out_w,
    const float* __restrict__ k_w, const float* __restrict__ v_w,
    const float* __restrict__ Cbuf, ushort* __restrict__ BF)
{
    int gid = blockIdx.x * 256 + threadIdx.x;
    int total = NTBL * NT_N * KS_N * 64;
    if (gid >= total) return;
    int tbl  = gid / (NT_N * KS_N * 64);
    int rem  = gid - tbl * (NT_N * KS_N * 64);
    int lane = rem & 63;
    int fs   = rem >> 6;          // nt*KS_N + s
    int s    = fs % KS_N;
    int nt   = fs / KS_N;
    int n    = nt * 16 + (lane & 15);
    int k0   = s * 32 + (lane >> 4) * 8;
    ushort* dst = BF + (size_t)tbl * TBL_SZ + (size_t)(fs * 64 + lane) * 8;
    #pragma unroll
    for (int j = 0; j < 8; j++) {
        int k = k0 + j;
        float val = 0.f;
        if (n < EDIM && k < EDIM) {
            switch (tbl) {
                case 0: val = q_w[(long)n * EDIM + k]; break;
                case 1: val = out_w[(long)n * EDIM + k]; break;
                case 2: val = k_w[(long)n * 2 * EDIM + k]; break;
                case 3: val = v_w[(long)n * 2 * EDIM + k]; break;
                case 4: val = Cbuf[2 * MM + (long)n * EDIM + k]; break;
                case 5: val = Cbuf[3 * MM + (long)n * EDIM + k]; break;
                case 6: val = Cbuf[0 * MM + (long)n * EDIM + k]; break;
                default: val = Cbuf[1 * MM + (long)n * EDIM + k]; break;
            }
        }
        dst[j] = f2bf(val);
    }
}

// ---------------- NodeK/V GEMM: 32 rows/wave, padded bf16 out ----------------
__global__ __launch_bounds__(256) void gemm_nodekv_kernel(
    const float* __restrict__ A, int M,
    const ushort* __restrict__ BF1, const ushort* __restrict__ BF2,
    ushort* __restrict__ C1h, ushort* __restrict__ C2h)
{
    const int lane = threadIdx.x & 63;
    const int wave = threadIdx.x >> 6;
    const int col  = lane & 15;
    const int quad = lane >> 4;
    const int m0   = (blockIdx.x * 4 + wave) * 32;
    if (m0 >= M) return;

    bf16x8 af[2][KS_N];
    bool rv[2];
    #pragma unroll
    for (int rb = 0; rb < 2; rb++) {
        int mr = m0 + rb * 16;
        rv[rb] = (mr < M);
        long arow = rv[rb] ? (long)(mr + col) : 0;
        load_afrag(A + arow * EDIM, quad, af[rb]);
    }

    #pragma unroll
    for (int nt = 0; nt < NT_N; nt++) {
        const ushort* bp1 = BF1 + (size_t)(nt * KS_N * 64 + lane) * 8;
        const ushort* bp2 = BF2 + (size_t)(nt * KS_N * 64 + lane) * 8;
        f32x4 acc1[2], acc2[2];
        #pragma unroll
        for (int rb = 0; rb < 2; rb++) {
            acc1[rb] = {0.f, 0.f, 0.f, 0.f};
            acc2[rb] = {0.f, 0.f, 0.f, 0.f};
        }
        #pragma unroll
        for (int s = 0; s < KS_N; s++) {
            bf16x8 b1 = *(const bf16x8*)(bp1 + (size_t)s * 64 * 8);
            bf16x8 b2 = *(const bf16x8*)(bp2 + (size_t)s * 64 * 8);
            #pragma unroll
            for (int rb = 0; rb < 2; rb++) {
                acc1[rb] = __builtin_amdgcn_mfma_f32_16x16x32_bf16(af[rb][s], b1, acc1[rb], 0, 0, 0);
                acc2[rb] = __builtin_amdgcn_mfma_f32_16x16x32_bf16(af[rb][s], b2, acc2[rb], 0, 0, 0);
            }
        }
        const int n = nt * 16 + col;
        if (n < EDIM) {
            const int np = n + (n >= HDIM ? 2 : 0);   // head-aligned pad
            #pragma unroll
            for (int rb = 0; rb < 2; rb++) {
                if (!rv[rb]) continue;
                #pragma unroll
                for (int r = 0; r < 4; r++) {
                    long ci = (long)(m0 + rb * 16 + quad * 4 + r) * KPAD + np;
                    C1h[ci] = f2bf(acc1[rb][r]);
                    C2h[ci] = f2bf(acc2[rb][r]);
                }
            }
        }
    }
    // zero the pad slots (86,87,174,175)
    if (lane < 32) {
        long row = m0 + lane;
        if (row < M) {
            C1h[row * KPAD + 86] = 0; C1h[row * KPAD + 87] = 0;
            C1h[row * KPAD + 174] = 0; C1h[row * KPAD + 175] = 0;
            C2h[row * KPAD + 86] = 0; C2h[row * KPAD + 87] = 0;
            C2h[row * KPAD + 174] = 0; C2h[row * KPAD + 175] = 0;
        }
    }
}

// ---------------- fused multi-output GEMM: 16 rows/block, wave = nt range ---
// A1 row index: i -> A1idx[i] -> (A1w ? A1w[that] : that). A1add elementwise.
// O1a/b/c: stride EDIM. O2a/b: stride2 (+pad2 head-aligned layout, pads zeroed).
__global__ __launch_bounds__(256) void fused_gemm_kernel(
    const float* __restrict__ A1, const int* __restrict__ A1idx,
    const int* __restrict__ A1w,
    const float* __restrict__ A1add, const float* __restrict__ A2, int M,
    const ushort* __restrict__ B1a, const ushort* __restrict__ B1b,
    const ushort* __restrict__ B1c,
    const float* __restrict__ bs1a, const float* __restrict__ bs1b,
    const float* __restrict__ bs1c,
    const ushort* __restrict__ B2a, const ushort* __restrict__ B2b,
    const float* __restrict__ bs2a,
    float* __restrict__ O1a, float* __restrict__ O1b, float* __restrict__ O1c,
    float* __restrict__ O2a, float* __restrict__ O2b,
    int stride2, int pad2)
{
    const int lane = threadIdx.x & 63;
    const int wave = threadIdx.x >> 6;
    const int col  = lane & 15;
    const int quad = lane >> 4;
    const int m0   = blockIdx.x * 16;
    int nt0 = wave * 3;
    int nt1 = nt0 + 3; if (nt1 > NT_N) nt1 = NT_N;

    long r1 = m0 + col;
    if (A1idx) r1 = (long)A1idx[r1];
    if (A1w)   r1 = (long)A1w[r1];
    bf16x8 af1[KS_N];
    if (A1add) load_afrag2(A1 + r1 * EDIM, A1add + (long)(m0 + col) * EDIM, quad, af1);
    else       load_afrag(A1 + r1 * EDIM, quad, af1);
    bf16x8 af2[KS_N];
    if (A2) load_afrag(A2 + (long)(m0 + col) * EDIM, quad, af2);

    for (int nt = nt0; nt < nt1; nt++) {
        const size_t boff = (size_t)(nt * KS_N * 64 + lane) * 8;
        f32x4 acc1 = {0.f,0.f,0.f,0.f}, acc2 = acc1, acc3 = acc1, acc4 = acc1, acc5 = acc1;
        #pragma unroll
        for (int s = 0; s < KS_N; s++) {
            const size_t so = boff + (size_t)s * 64 * 8;
            acc1 = __builtin_amdgcn_mfma_f32_16x16x32_bf16(af1[s], *(const bf16x8*)(B1a + so), acc1, 0, 0, 0);
            if (B1b) acc2 = __builtin_amdgcn_mfma_f32_16x16x32_bf16(af1[s], *(const bf16x8*)(B1b + so), acc2, 0, 0, 0);
            if (B1c) acc3 = __builtin_amdgcn_mfma_f32_16x16x32_bf16(af1[s], *(const bf16x8*)(B1c + so), acc3, 0, 0, 0);
            if (B2a) acc4 = __builtin_amdgcn_mfma_f32_16x16x32_bf16(af2[s], *(const bf16x8*)(B2a + so), acc4, 0, 0, 0);
            if (B2b) acc5 = __builtin_amdgcn_mfma_f32_16x16x32_bf16(af2[s], *(const bf16x8*)(B2b + so), acc5, 0, 0, 0);
        }
        const int n = nt * 16 + col;
        if (n < EDIM) {
            const float b1 = bs1a ? bs1a[n] : 0.f;
            const float b2 = bs1b ? bs1b[n] : 0.f;
            const float b3 = bs1c ? bs1c[n] : 0.f;
            const float b4 = bs2a ? bs2a[n] : 0.f;
            const int np = n + ((pad2 && n >= HDIM) ? 2 : 0);
            #pragma unroll
            for (int r = 0; r < 4; r++) {
                long row = m0 + quad * 4 + r;
                long ci  = row * EDIM + n;
                O1a[ci] = acc1[r] + b1;
                if (O1b) O1b[ci] = acc2[r] + b2;
                if (O1c) O1c[ci] = acc3[r] + b3;
                long c2 = row * (long)stride2 + np;
                if (O2a) O2a[c2] = acc4[r] + b4;
                if (O2b) O2b[c2] = acc5[r];
            }
        }
    }
    if (pad2 && wave == 0 && lane < 16) {
        long row = m0 + lane;
        if (O2a) {
            O2a[row * (long)stride2 + 86]  = 0.f; O2a[row * (long)stride2 + 87]  = 0.f;
            O2a[row * (long)stride2 + 174] = 0.f; O2a[row * (long)stride2 + 175] = 0.f;
        }
        if (O2b) {
            O2b[row * (long)stride2 + 86]  = 0.f; O2b[row * (long)stride2 + 87]  = 0.f;
            O2b[row * (long)stride2 + 174] = 0.f; O2b[row * (long)stride2 + 175] = 0.f;
        }
    }
}

// ---------------- output projection: C = A1@out_w^T + agg0@M0^T + agg1@M1^T + bias
__global__ __launch_bounds__(256) void gemm_out3_kernel(
    const float* __restrict__ A1,   // AO, lda = EDIM
    const float* __restrict__ A2,   // AGG, lda = 2*EDIM
    int M,
    const ushort* __restrict__ BFo, const ushort* __restrict__ BFm0,
    const ushort* __restrict__ BFm1,
    const float* __restrict__ bias, float* __restrict__ C)
{
    const int lane = threadIdx.x & 63;
    const int wave = threadIdx.x >> 6;
    const int col  = lane & 15;
    const int quad = lane >> 4;
    const int m0   = blockIdx.x * 16;
    int nt0 = wave * 3;
    int nt1 = nt0 + 3; if (nt1 > NT_N) nt1 = NT_N;
    const long arow = m0 + col;

    bf16x8 afo[KS_N], afa[KS_N], afb[KS_N];
    load_afrag(A1 + arow * EDIM, quad, afo);
    load_afrag(A2 + arow * 2 * EDIM, quad, afa);
    load_afrag(A2 + arow * 2 * EDIM + EDIM, quad, afb);

    for (int nt = nt0; nt < nt1; nt++) {
        const size_t boff = (size_t)(nt * KS_N * 64 + lane) * 8;
        f32x4 acc = {0.f, 0.f, 0.f, 0.f};
        #pragma unroll
        for (int s = 0; s < KS_N; s++) {
            const size_t so = boff + (size_t)s * 64 * 8;
            acc = __builtin_amdgcn_mfma_f32_16x16x32_bf16(afo[s], *(const bf16x8*)(BFo  + so), acc, 0, 0, 0);
            acc = __builtin_amdgcn_mfma_f32_16x16x32_bf16(afa[s], *(const bf16x8*)(BFm0 + so), acc, 0, 0, 0);
            acc = __builtin_amdgcn_mfma_f32_16x16x32_bf16(afb[s], *(const bf16x8*)(BFm1 + so), acc, 0, 0, 0);
        }
        const int n = nt * 16 + col;
        if (n < EDIM) {
            const float bb = bias ? bias[n] : 0.f;
            #pragma unroll
            for (int r = 0; r < 4; r++) {
                long ci = (long)(m0 + quad * 4 + r) * EDIM + n;
                C[ci] = acc[r] + bb;
            }
        }
    }
}

// ---------------- per-sample attention: 2 samples / 256-thread block --------
__global__ __launch_bounds__(256) void attn_kernel(
    const int* __restrict__ neighbors, const int* __restrict__ eidx,
    const float* __restrict__ Q, const float* __restrict__ QT0,
    const float* __restrict__ QT1, const float* __restrict__ TV,
    const float* __restrict__ edgef,
    const int* __restrict__ winner,
    const ushort* __restrict__ NodeK, const ushort* __restrict__ NodeV,
    const float* __restrict__ H1K, const float* __restrict__ H1V,
    float* __restrict__ AO, float* __restrict__ AGG)
{
    const int tid = threadIdx.x;
    const int b0  = blockIdx.x * 2;

    __shared__ __align__(16) float sq[2][520];   // padded q(176) + qt0(172) + qt1(172)
    __shared__ float sef[2][KNB * SKP];
    __shared__ float swv[2][2][KNB];
    __shared__ int   snb[2][KNB], sei[2][KNB], swin[2][KNB], spad[2][KNB];

    // phase A: meta + q staging
    if (tid < 2 * KNB) {
        int s = tid / KNB, kk = tid - s * KNB;
        int b = b0 + s;
        int nb = neighbors[b * KNB + kk];
        snb[s][kk]  = nb;
        sei[s][kk]  = eidx[b * KNB + kk];
        swin[s][kk] = winner ? winner[nb] : -1;
        spad[s][kk] = (nb == 0) ? 1 : 0;
    }
    for (int i = tid; i < 2 * EDIM; i += 256) {
        int s = i / EDIM, d = i - s * EDIM;
        long bi = (long)(b0 + s) * EDIM + d;
        sq[s][d + (d >= HDIM ? 2 : 0)] = Q[bi];
        sq[s][176 + d]                 = QT0[bi];
        sq[s][348 + d]                 = QT1[bi];
    }
    if (tid < 8) {   // zero q pads
        int s = tid >> 2, p = tid & 3;
        const int pos[4] = {86, 87, 174, 175};
        sq[s][pos[p]] = 0.f;
    }
    __syncthreads();

    // phase B: all-pad fixup + ef staging (read ONCE from HBM into LDS)
    if (tid < 2) {
        int c = 0;
        for (int k = 0; k < KNB; k++) c += spad[tid][k];
        if (c == KNB) spad[tid][0] = 0;
    }
    for (int task = tid; task < 2 * KNB * 43; task += 256) {
        int s = task / (KNB * 43);
        int r = task - s * (KNB * 43);
        int kk = r / 43, c = r - kk * 43, e = c * 4;
        float4 v = *(const float4*)(edgef + (long)sei[s][kk] * EDIM + e);
        float* p = &sef[s][kk * SKP + e];
        p[0] = v.x; p[1] = v.y; p[2] = v.z; p[3] = v.w;
    }
    __syncthreads();

    // phase C: scores. 160 threads: (s, kk, h, part)
    if (tid < 2 * KNB * 4) {
        int s = tid >= 80 ? 1 : 0;
        int r = tid - s * 80;
        int kk = r >> 2, h = (r >> 1) & 1, part = r & 1;
        const int off = h * 88 + part * 44;       // padded head offset
        const float* qb = &sq[s][off];
        float sc = 0.f;
        int ww = swin[s][kk];
        if (ww >= 0) {
            const float* kp = H1K + (long)ww * KPAD + off;
            #pragma unroll
            for (int i = 0; i < 11; i++) {
                float4 kv = *(const float4*)(kp + 4 * i);
                float4 qv = *(const float4*)(qb + 4 * i);
                sc += kv.x * qv.x + kv.y * qv.y + kv.z * qv.z + kv.w * qv.w;
            }
        } else {
            const ushort* kp = NodeK + (long)snb[s][kk] * KPAD + off;
            #pragma unroll
            for (int i = 0; i < 11; i++) {
                ushort4 kv = *(const ushort4*)(kp + 4 * i);
                float4 qv = *(const float4*)(qb + 4 * i);
                sc += bf2f(kv.x) * qv.x + bf2f(kv.y) * qv.y
                    + bf2f(kv.z) * qv.z + bf2f(kv.w) * qv.w;
            }
        }
        const float* ep = &sef[s][kk * SKP + part * HDIM];
        const float* qt = &sq[s][176 + h * EDIM + part * HDIM];
        for (int d = 0; d < HDIM; d++) sc += ep[d] * qt[d];
        sc += __shfl_xor(sc, 1, 64);
        if (part == 0)
            swv[s][h][kk] = spad[s][kk] ? -1e9f : (sc * 0.10783277320343841f); // 1/sqrt(86)
    }
    __syncthreads();

    // phase D: softmax, wave per (s,h)
    {
        int wv = tid >> 6, lane = tid & 63;
        int s = wv >> 1, h = wv & 1;
        float v = (lane < KNB) ? swv[s][h][lane] : -1e30f;
        float mx = v;
        mx = fmaxf(mx, __shfl_xor(mx, 1, 64));
        mx = fmaxf(mx, __shfl_xor(mx, 2, 64));
        mx = fmaxf(mx, __shfl_xor(mx, 4, 64));
        mx = fmaxf(mx, __shfl_xor(mx, 8, 64));
        mx = fmaxf(mx, __shfl_xor(mx, 16, 64));
        float ex  = (lane < KNB) ? __expf(v - mx) : 0.f;
        float sum = ex;
        sum += __shfl_xor(sum, 1, 64);
        sum += __shfl_xor(sum, 2, 64);
        sum += __shfl_xor(sum, 4, 64);
        sum += __shfl_xor(sum, 8, 64);
        sum += __shfl_xor(sum, 16, 64);
        if (lane < KNB) swv[s][h][lane] = ex * (1.f / sum);
    }
    __syncthreads();

    // phase E: output + agg, coalesced per-sample rows
    for (int s = 0; s < 2; s++) {
        if (tid < EDIM) {
            const int vidx = tid + (tid >= HDIM ? 2 : 0);
            float acc = 0.f, a0 = 0.f, a1 = 0.f;
            #pragma unroll 5
            for (int kk = 0; kk < KNB; kk++) {
                float w0 = swv[s][0][kk], w1 = swv[s][1][kk];
                int ww = swin[s][kk];
                float vv = (ww >= 0) ? H1V[(long)ww * KPAD + vidx]
                                     : bf2f(NodeV[(long)snb[s][kk] * KPAD + vidx]);
                float ev = sef[s][kk * SKP + tid];
                acc += (tid < HDIM ? w0 : w1) * vv;
                a0 += w0 * ev;
                a1 += w1 * ev;
            }
            long b = b0 + s;
            AO [b * EDIM + tid]            = acc + TV[b * EDIM + tid];
            AGG[b * 2 * EDIM + tid]        = a0;
            AGG[b * 2 * EDIM + EDIM + tid] = a1;
        }
    }
}

extern "C" void kernel_launch(void* const* d_in, const int* in_sizes, int n_in,
                              void* d_out, int out_size, void* d_ws, size_t ws_size,
                              hipStream_t stream)
{
    const int*   nodes   = (const int*)d_in[0];
    const float* ts      = (const float*)d_in[1];
    const int*   neigh   = (const int*)d_in[2];
    const int*   edgeidx = (const int*)d_in[3];
    const float* nodef   = (const float*)d_in[4];
    const float* edgef   = (const float*)d_in[5];
    const float* time_w  = (const float*)d_in[6];
    const float* time_b  = (const float*)d_in[7];
    const float* q_w     = (const float*)d_in[8];
    const float* k_w     = (const float*)d_in[9];
    const float* v_w     = (const float*)d_in[10];
    const float* bq      = (const float*)d_in[11];
    const float* bv      = (const float*)d_in[13];
    const float* out_w   = (const float*)d_in[14];
    const float* out_b   = (const float*)d_in[15];
    float* out = (float*)d_out;

    char* wsp = (char*)d_ws;
    size_t off = 0;
    auto alloc = [&](size_t bytes) -> void* {
        void* p = wsp + off;
        off += (bytes + 255) & ~(size_t)255;
        return p;
    };
    const size_t SE = (size_t)NSMP * EDIM;
    float* t_enc = (float*)alloc(SE * 4);
    float* Qb    = (float*)alloc(SE * 4);
    float* QT0   = (float*)alloc(SE * 4);
    float* QT1   = (float*)alloc(SE * 4);
    float* TV    = (float*)alloc(SE * 4);
    float* AO    = (float*)alloc(SE * 4);
    float* H1    = (float*)alloc(SE * 4);
    float* H1K   = (float*)alloc((size_t)NSMP * KPAD * 4);
    float* H1V   = (float*)alloc((size_t)NSMP * KPAD * 4);
    float* AGG   = (float*)alloc((size_t)NSMP * 2 * EDIM * 4);
    float* Cbuf  = (float*)alloc((size_t)(4 * MM + 2 * EDIM) * 4);
    int*   winner = (int*)alloc((size_t)NNODES * 4);
    ushort* NodeK = (ushort*)alloc((size_t)NNODES * KPAD * 2);
    ushort* NodeV = (ushort*)alloc((size_t)NNODES * KPAD * 2);
    ushort* BF    = (ushort*)alloc((size_t)NTBL * TBL_SZ * 2);
    if (off > ws_size) return;

    const ushort* BFq   = BF + 0 * TBL_SZ;
    const ushort* BFout = BF + 1 * TBL_SZ;
    const ushort* BFkE  = BF + 2 * TBL_SZ;
    const ushort* BFvE  = BF + 3 * TBL_SZ;
    const ushort* BFW0  = BF + 4 * TBL_SZ;
    const ushort* BFW1  = BF + 5 * TBL_SZ;
    const ushort* BFM0  = BF + 6 * TBL_SZ;
    const ushort* BFM1  = BF + 7 * TBL_SZ;
    const float* bqt0 = Cbuf + 4 * MM;
    const float* bqt1 = Cbuf + 4 * MM + EDIM;

    dim3 blk(256);
    const int gF = NSMP / 16;                   // 750 blocks, wave = nt range

    winner_init_kernel<<<(NNODES + 255) / 256, blk, 0, stream>>>(winner);
    winner_scatter_kernel<<<(NSMP + 255) / 256, blk, 0, stream>>>(nodes, winner);
    composites_kernel<<<(4 * MM + 2 * EDIM + 255) / 256, blk, 0, stream>>>(
        out_w, v_w, k_w, q_w, bq, Cbuf);
    preswizzle_kernel<<<(NTBL * NT_N * KS_N * 64 + 255) / 256, blk, 0, stream>>>(
        q_w, out_w, k_w, v_w, Cbuf, BF);
    time_enc_kernel<<<(NSMP * EDIM + 255) / 256, blk, 0, stream>>>(ts, time_w, time_b, t_enc);

    // NodeK/V (bf16, padded rows)
    gemm_nodekv_kernel<<<(NNODES + 127) / 128, blk, 0, stream>>>(
        nodef, NNODES, BFkE, BFvE, NodeK, NodeV);

    // Layer 1 fused: A1 = nf[nodes] + t -> Q, QT0, QT1 ; A2 = t -> TV
    fused_gemm_kernel<<<gF, blk, 0, stream>>>(
        nodef, nodes, nullptr, t_enc, t_enc, NSMP,
        BFq, BFW0, BFW1, bq, bqt0, bqt1,
        BFvE, nullptr, bv,
        Qb, QT0, QT1, TV, nullptr, EDIM, 0);

    attn_kernel<<<NSMP / 2, blk, 0, stream>>>(neigh, edgeidx, Qb, QT0, QT1, TV,
        edgef, nullptr, NodeK, NodeV, nullptr, nullptr, AO, AGG);
    gemm_out3_kernel<<<gF, blk, 0, stream>>>(AO, AGG, NSMP,
        BFout, BFM0, BFM1, out_b, H1);

    // Layer 2 fused: A1 = h1[winner[nodes]] + t -> Q, QT0, QT1 ; A2 = H1 -> H1K/H1V
    fused_gemm_kernel<<<gF, blk, 0, stream>>>(
        H1, nodes, winner, t_enc, H1, NSMP,
        BFq, BFW0, BFW1, bq, bqt0, bqt1,
        BFkE, BFvE, nullptr,
        Qb, QT0, QT1, H1K, H1V, KPAD, 1);

    attn_kernel<<<NSMP / 2, blk, 0, stream>>>(neigh, edgeidx, Qb, QT0, QT1, TV,
        edgef, winner, NodeK, NodeV, H1K, H1V, AO, AGG);
    gemm_out3_kernel<<<gF, blk, 0, stream>>>(AO, AGG, NSMP,
        BFout, BFM0, BFM1, out_b, out);
}